// Round 1
// baseline (1148.012 us; speedup 1.0000x reference)
//
#include <hip/hip_runtime.h>
#include <hip/hip_bf16.h>

typedef __attribute__((ext_vector_type(8))) short short8;
typedef __attribute__((ext_vector_type(4))) float f32x4;

#define INF_F 3.4e38f

__device__ __forceinline__ void gload16(const void* g, void* l) {
    __builtin_amdgcn_global_load_lds((const __attribute__((address_space(1))) unsigned*)g,
                                     (__attribute__((address_space(3))) unsigned*)l, 16, 0, 0);
}

// ---------------- init ----------------
__global__ void k_init(float* ps_sq, int* cand_cnt, float* cand_val) {
    int i = blockIdx.x * 256 + threadIdx.x;
    if (i < 8192) ((unsigned*)ps_sq)[i] = 0x7f800000u;   // +inf
    if (i < 8)    cand_cnt[i] = 0;
    if (i < 64)   ((unsigned*)cand_val)[i] = 0x7f800000u;
}

// ---------------- fp32 -> bf16 + row norms (512 cols) ----------------
__global__ void k_conv(const float* __restrict__ in, unsigned short* __restrict__ outb,
                       float* __restrict__ norm, int rows) {
    int t = threadIdx.x, wid = t >> 6, lane = t & 63;
    int row = blockIdx.x * 4 + wid;
    if (row >= rows) return;
    const float4* p = (const float4*)(in + (size_t)row * 512) + lane * 2;
    float4 a = p[0], b = p[1];
    float n = a.x*a.x + a.y*a.y + a.z*a.z + a.w*a.w
            + b.x*b.x + b.y*b.y + b.z*b.z + b.w*b.w;
    float vals[8] = {a.x, a.y, a.z, a.w, b.x, b.y, b.z, b.w};
    unsigned short h[8];
    #pragma unroll
    for (int e = 0; e < 8; ++e) {
        unsigned u = __float_as_uint(vals[e]);
        h[e] = (unsigned short)((u + 0x7fffu + ((u >> 16) & 1u)) >> 16);  // RNE
    }
    *(uint4*)(outb + (size_t)row * 512 + lane * 8) = *(uint4*)h;
    #pragma unroll
    for (int s = 1; s < 64; s <<= 1) n += __shfl_xor(n, s, 64);
    if (lane == 0) norm[row] = n;
}

// ---------------- fused GEMM + per-row min (m97 structure) ----------------
// C[i][j] = fv[i].mb[j]; track min_j (mn[j] - 2*C[i][j]) per row; add fn[i], atomicMin.
__global__ __launch_bounds__(256, 2)
void k_gemm_min(const unsigned short* __restrict__ A, const unsigned short* __restrict__ B,
                const float* __restrict__ fnorm, const float* __restrict__ mnorm,
                float* __restrict__ ps_sq) {
    __shared__ unsigned short At[128 * 64];
    __shared__ unsigned short Bt[128 * 64];
    int tid = threadIdx.x, wid = tid >> 6, lane = tid & 63;
    int brow = blockIdx.y * 128;
    int bcol = blockIdx.x * 128;
    int wm = (wid >> 1) * 64, wn = (wid & 1) * 64;

    f32x4 acc[4][4] = {};
    int lr = lane >> 3, lk = (lane & 7) * 8;

    for (int k0 = 0; k0 < 512; k0 += 64) {
        #pragma unroll
        for (int c = 0; c < 4; ++c) {
            int ch = wid + c * 4;                 // chunk 0..15, 8 rows each
            int row = ch * 8 + lr;
            gload16(A + (size_t)(brow + row) * 512 + k0 + lk, &At[ch * 512]);
            int srow = bcol + row; if (srow > 24999) srow = 24999;   // clamp OOB cols
            gload16(B + (size_t)srow * 512 + k0 + lk, &Bt[ch * 512]);
        }
        __syncthreads();
        #pragma unroll
        for (int kk = 0; kk < 2; ++kk) {
            short8 af[4], bf[4];
            int ko = kk * 32 + (lane >> 4) * 8;
            #pragma unroll
            for (int mi = 0; mi < 4; ++mi)
                af[mi] = *(const short8*)&At[(wm + mi * 16 + (lane & 15)) * 64 + ko];
            #pragma unroll
            for (int ni = 0; ni < 4; ++ni)
                bf[ni] = *(const short8*)&Bt[(wn + ni * 16 + (lane & 15)) * 64 + ko];
            #pragma unroll
            for (int mi = 0; mi < 4; ++mi)
                #pragma unroll
                for (int ni = 0; ni < 4; ++ni)
                    acc[mi][ni] = __builtin_amdgcn_mfma_f32_16x16x32_bf16(af[mi], bf[ni], acc[mi][ni], 0, 0, 0);
        }
        __syncthreads();
    }

    float mnv[4];
    #pragma unroll
    for (int ni = 0; ni < 4; ++ni) {
        int col = bcol + wn + ni * 16 + (lane & 15);
        mnv[ni] = (col < 25000) ? mnorm[col] : INF_F;
    }
    #pragma unroll
    for (int mi = 0; mi < 4; ++mi) {
        #pragma unroll
        for (int r = 0; r < 4; ++r) {
            float v = INF_F;
            #pragma unroll
            for (int ni = 0; ni < 4; ++ni) v = fminf(v, mnv[ni] - 2.0f * acc[mi][ni][r]);
            #pragma unroll
            for (int s = 1; s < 16; s <<= 1) v = fminf(v, __shfl_xor(v, s, 64));
            if ((lane & 15) == 0) {
                int row = brow + wm + mi * 16 + (lane >> 4) * 4 + r;
                float sq = v + fnorm[row];
                atomicMin((unsigned*)&ps_sq[row], __float_as_uint(sq));  // sq >= 0
            }
        }
    }
}

// ---------------- output 0: sqrt ----------------
__global__ void k_out0(const float* __restrict__ ps_sq, float* __restrict__ out0) {
    int i = blockIdx.x * 256 + threadIdx.x;
    if (i < 8192) out0[i] = sqrtf(fmaxf(ps_sq[i], 0.0f));
}

// ---------------- per-batch candidate gather (margin-robust argmax) ----------------
__global__ void k_cand(const float* __restrict__ ps_sq, int* cand_cnt, int* cand_idx) {
    __shared__ float smax[4];
    __shared__ int scnt;
    int b = blockIdx.x, t = threadIdx.x, wid = t >> 6, lane = t & 63;
    const float* base = ps_sq + b * 1024;
    float v[4]; float m = -INF_F;
    #pragma unroll
    for (int i = 0; i < 4; ++i) { v[i] = base[t + i * 256]; m = fmaxf(m, v[i]); }
    #pragma unroll
    for (int s = 1; s < 64; s <<= 1) m = fmaxf(m, __shfl_xor(m, s, 64));
    if (lane == 0) smax[wid] = m;
    if (t == 0) scnt = 0;
    __syncthreads();
    float bm = fmaxf(fmaxf(smax[0], smax[1]), fmaxf(smax[2], smax[3]));
    #pragma unroll
    for (int i = 0; i < 4; ++i) {
        if (v[i] >= bm - 8.0f) {            // margin >> 2x worst-case bf16 dot error
            int s = atomicAdd(&scnt, 1);
            if (s < 8) cand_idx[b * 8 + s] = b * 1024 + t + i * 256;
        }
    }
    __syncthreads();
    if (t == 0) cand_cnt[b] = min(scnt, 8);
}

// ---------------- exact fp32 min-dist for candidates ----------------
__global__ void k_exact(const float* __restrict__ fv, const float* __restrict__ mb,
                        const int* __restrict__ cand_cnt, const int* __restrict__ cand_idx,
                        float* cand_val) {
    int batch = blockIdx.z, slot = blockIdx.y, chunk = blockIdx.x;
    if (slot >= cand_cnt[batch]) return;
    __shared__ float fs[512];
    __shared__ float wmin[4];
    int t = threadIdx.x, wid = t >> 6, lane = t & 63;
    int pix = cand_idx[batch * 8 + slot];
    fs[t] = fv[(size_t)pix * 512 + t];
    fs[t + 256] = fv[(size_t)pix * 512 + t + 256];
    __syncthreads();
    int r0 = chunk * 3125, r1 = r0 + 3125;     // 25000/8
    float lmin = INF_F;
    const float* fp = fs + lane * 8;
    for (int row = r0 + wid; row < r1; row += 4) {
        const float4* mp = (const float4*)(mb + (size_t)row * 512) + lane * 2;
        float4 m0 = mp[0], m1 = mp[1];
        float p = 0.f, d;
        d = m0.x - fp[0]; p += d * d;  d = m0.y - fp[1]; p += d * d;
        d = m0.z - fp[2]; p += d * d;  d = m0.w - fp[3]; p += d * d;
        d = m1.x - fp[4]; p += d * d;  d = m1.y - fp[5]; p += d * d;
        d = m1.z - fp[6]; p += d * d;  d = m1.w - fp[7]; p += d * d;
        #pragma unroll
        for (int s = 1; s < 64; s <<= 1) p += __shfl_xor(p, s, 64);
        lmin = fminf(lmin, p);
    }
    if (lane == 0) wmin[wid] = lmin;
    __syncthreads();
    if (t == 0) {
        float v = fminf(fminf(wmin[0], wmin[1]), fminf(wmin[2], wmin[3]));
        atomicMin((unsigned*)&cand_val[batch * 8 + slot], __float_as_uint(v));
    }
}

// ---------------- exact argmax (ties -> lower pixel index, matches jnp.argmax) ----------------
__global__ void k_argmax(const int* cand_cnt, const int* cand_idx, const float* cand_val, int* sel_idx) {
    int b = blockIdx.x, lane = threadIdx.x;
    int n = cand_cnt[b];
    float v = -INF_F; int idx = 0x7fffffff;
    if (lane < n) { v = cand_val[b * 8 + lane]; idx = cand_idx[b * 8 + lane]; }
    #pragma unroll
    for (int s = 1; s < 8; s <<= 1) {
        float ov = __shfl_xor(v, s, 64); int oi = __shfl_xor(idx, s, 64);
        if (ov > v || (ov == v && oi < idx)) { v = ov; idx = oi; }
    }
    if (lane == 0) sel_idx[b] = idx;
}

// ---------------- exact fp32 distances of the 8 winners to all mb ----------------
__global__ void k_dists(const float* __restrict__ fv, const float* __restrict__ mb,
                        const int* __restrict__ sel_idx, float* __restrict__ exact_d) {
    __shared__ float fs[8 * 512];
    int t = threadIdx.x;
    for (int i = t; i < 4096; i += 256) {
        int b = i >> 9, k = i & 511;
        fs[i] = fv[(size_t)sel_idx[b] * 512 + k];
    }
    __syncthreads();
    int wid = t >> 6, lane = t & 63;
    int rbase = blockIdx.x * 256 + wid * 64;
    for (int i = 0; i < 64; ++i) {
        int r = rbase + i;
        if (r >= 25000) break;
        const float4* mp = (const float4*)(mb + (size_t)r * 512) + lane * 2;
        float4 m0 = mp[0], m1 = mp[1];
        float mv[8] = {m0.x, m0.y, m0.z, m0.w, m1.x, m1.y, m1.z, m1.w};
        for (int b = 0; b < 8; ++b) {
            const float* fp = fs + b * 512 + lane * 8;
            float p = 0.f;
            #pragma unroll
            for (int e = 0; e < 8; ++e) { float d = mv[e] - fp[e]; p += d * d; }
            #pragma unroll
            for (int s = 1; s < 64; s <<= 1) p += __shfl_xor(p, s, 64);
            if (lane == 0) exact_d[b * 25000 + r] = p;
        }
    }
}

// ---------------- top-b (ascending dist, jax tie order) + softmax -> image_scores ----------------
__global__ void k_final(const float* __restrict__ exact_d, const int* __restrict__ bptr,
                        float* __restrict__ out_img) {
    __shared__ float rv[4]; __shared__ int ri[4];
    __shared__ float seld[128];
    __shared__ float lastV_s; __shared__ int lastI_s;
    int b = blockIdx.x, t = threadIdx.x, wid = t >> 6, lane = t & 63;
    int bval = bptr[0]; if (bval > 128) bval = 128; if (bval < 1) bval = 1;
    const float* dv = exact_d + b * 25000;
    float lastV = -INF_F; int lastI = -1;
    for (int k = 0; k < bval; ++k) {
        float bv = INF_F; int bi = 0x7fffffff;
        for (int r = t; r < 25000; r += 256) {
            float vv = dv[r];
            bool after = (vv > lastV) || (vv == lastV && r > lastI);
            if (after && (vv < bv || (vv == bv && r < bi))) { bv = vv; bi = r; }
        }
        #pragma unroll
        for (int s = 1; s < 64; s <<= 1) {
            float ov = __shfl_xor(bv, s, 64); int oi = __shfl_xor(bi, s, 64);
            if (ov < bv || (ov == bv && oi < bi)) { bv = ov; bi = oi; }
        }
        if (lane == 0) { rv[wid] = bv; ri[wid] = bi; }
        __syncthreads();
        if (t == 0) {
            float fbv = rv[0]; int fbi = ri[0];
            for (int w = 1; w < 4; ++w)
                if (rv[w] < fbv || (rv[w] == fbv && ri[w] < fbi)) { fbv = rv[w]; fbi = ri[w]; }
            seld[k] = sqrtf(fbv);
            lastV_s = fbv; lastI_s = fbi;
        }
        __syncthreads();
        lastV = lastV_s; lastI = lastI_s;
    }
    if (t == 0) {
        float d0 = seld[0];
        float img = d0;
        if (bval > 1) {
            float m = -INF_F;
            for (int k = 0; k < bval; ++k) m = fmaxf(m, seld[k]);
            float s = 0.f;
            for (int k = 0; k < bval; ++k) s += expf(seld[k] - m);
            float p0 = expf(seld[0] - m) / s;
            img = d0 * (1.0f - p0);
        }
        out_img[b] = img;
    }
}

extern "C" void kernel_launch(void* const* d_in, const int* in_sizes, int n_in,
                              void* d_out, int out_size, void* d_ws, size_t ws_size,
                              hipStream_t stream) {
    const float* fv = (const float*)d_in[0];   // 8192 x 512
    const float* mb = (const float*)d_in[1];   // 25000 x 512
    const int*   bp = (const int*)d_in[2];     // scalar b
    float* out = (float*)d_out;                // [0..8191]=pixel_scores, [8192..8199]=image_scores

    char* w = (char*)d_ws;                     // needs ~35 MB
    unsigned short* fvb = (unsigned short*)w;                       // 8,388,608 B
    unsigned short* mbb = (unsigned short*)(w + 8388608);           // 25,600,000 B
    size_t o = 8388608 + 25600000;
    float* fnorm   = (float*)(w + o); o += 32768;
    float* mnorm   = (float*)(w + o); o += 100352;
    float* ps_sq   = (float*)(w + o); o += 32768;
    int*   cand_cnt= (int*)(w + o);   o += 256;
    int*   cand_idx= (int*)(w + o);   o += 256;
    float* cand_val= (float*)(w + o); o += 256;
    int*   sel     = (int*)(w + o);   o += 256;
    float* exact_d = (float*)(w + o); o += 800000;

    k_init<<<32, 256, 0, stream>>>(ps_sq, cand_cnt, cand_val);
    k_conv<<<2048, 256, 0, stream>>>(fv, fvb, fnorm, 8192);
    k_conv<<<6250, 256, 0, stream>>>(mb, mbb, mnorm, 25000);
    k_gemm_min<<<dim3(196, 64), 256, 0, stream>>>(fvb, mbb, fnorm, mnorm, ps_sq);
    k_out0<<<32, 256, 0, stream>>>(ps_sq, out);
    k_cand<<<8, 256, 0, stream>>>(ps_sq, cand_cnt, cand_idx);
    k_exact<<<dim3(8, 8, 8), 256, 0, stream>>>(fv, mb, cand_cnt, cand_idx, cand_val);
    k_argmax<<<8, 64, 0, stream>>>(cand_cnt, cand_idx, cand_val, sel);
    k_dists<<<98, 256, 0, stream>>>(fv, mb, sel, exact_d);
    k_final<<<8, 256, 0, stream>>>(exact_d, bp, out + 8192);
}

// Round 2
// 755.771 us; speedup vs baseline: 1.5190x; 1.5190x over previous
//
#include <hip/hip_runtime.h>
#include <hip/hip_bf16.h>

typedef __attribute__((ext_vector_type(8))) short short8;
typedef __attribute__((ext_vector_type(4))) float f32x4;

#define INF_F 3.4e38f

__device__ __forceinline__ void gload16(const void* g, void* l) {
    __builtin_amdgcn_global_load_lds((const __attribute__((address_space(1))) unsigned*)g,
                                     (__attribute__((address_space(3))) unsigned*)l, 16, 0, 0);
}

// ---------------- init ----------------
__global__ void k_init(float* ps_sq, int* ncand, float* cand_val) {
    int i = blockIdx.x * 256 + threadIdx.x;
    if (i < 8192) ((unsigned*)ps_sq)[i] = 0x7f800000u;   // +inf
    if (i == 0)   ncand[0] = 0;
    if (i < 64)   ((unsigned*)cand_val)[i] = 0x7f800000u;
}

// ---------------- fp32 -> bf16 + row norms (512 cols) ----------------
__global__ void k_conv(const float* __restrict__ in, unsigned short* __restrict__ outb,
                       float* __restrict__ norm, int rows) {
    int t = threadIdx.x, wid = t >> 6, lane = t & 63;
    int row = blockIdx.x * 4 + wid;
    if (row >= rows) return;
    const float4* p = (const float4*)(in + (size_t)row * 512) + lane * 2;
    float4 a = p[0], b = p[1];
    float n = a.x*a.x + a.y*a.y + a.z*a.z + a.w*a.w
            + b.x*b.x + b.y*b.y + b.z*b.z + b.w*b.w;
    float vals[8] = {a.x, a.y, a.z, a.w, b.x, b.y, b.z, b.w};
    unsigned short h[8];
    #pragma unroll
    for (int e = 0; e < 8; ++e) {
        unsigned u = __float_as_uint(vals[e]);
        h[e] = (unsigned short)((u + 0x7fffu + ((u >> 16) & 1u)) >> 16);  // RNE
    }
    *(uint4*)(outb + (size_t)row * 512 + lane * 8) = *(uint4*)h;
    #pragma unroll
    for (int s = 1; s < 64; s <<= 1) n += __shfl_xor(n, s, 64);
    if (lane == 0) norm[row] = n;
}

// ---------------- fused GEMM + per-row min ----------------
// T2 swizzle: LDS dest stays linear (global_load_lds), global SOURCE column is
// pre-permuted per lane; ds_read applies the same XOR. XCD-chunked 1-D grid.
__global__ __launch_bounds__(256, 2)
void k_gemm_min(const unsigned short* __restrict__ A, const unsigned short* __restrict__ B,
                const float* __restrict__ fnorm, const float* __restrict__ mnorm,
                float* __restrict__ ps_sq) {
    __shared__ unsigned short At[128 * 64];
    __shared__ unsigned short Bt[128 * 64];
    int tid = threadIdx.x, wid = tid >> 6, lane = tid & 63;

    // grid = 12544 blocks: xcd = bid&7 owns an 8-row-block A panel (1MB, L2-resident)
    // and sweeps all 196 col-blocks; 8 consecutive blocks share one B-tile.
    int bid = blockIdx.x;
    int pos = bid >> 3;
    int rb = ((bid & 7) << 3) | (pos & 7);   // 0..63
    int cb = pos >> 3;                        // 0..195
    int brow = rb * 128, bcol = cb * 128;
    int wm = (wid >> 1) * 64, wn = (wid & 1) * 64;

    f32x4 acc[4][4] = {};
    int lr = lane >> 3;
    int lkswz = ((lane & 7) ^ lr) * 8;        // pre-swizzled source column (elems)

    for (int k0 = 0; k0 < 512; k0 += 64) {
        #pragma unroll
        for (int c = 0; c < 4; ++c) {
            int ch = wid + c * 4;                 // chunk 0..15, 8 rows each
            int row = ch * 8 + lr;
            gload16(A + (size_t)(brow + row) * 512 + k0 + lkswz, &At[ch * 512]);
            int srow = bcol + row; if (srow > 24999) srow = 24999;   // clamp OOB cols
            gload16(B + (size_t)srow * 512 + k0 + lkswz, &Bt[ch * 512]);
        }
        __syncthreads();
        #pragma unroll
        for (int kk = 0; kk < 2; ++kk) {
            short8 af[4], bf[4];
            int ko = kk * 32 + (lane >> 4) * 8;
            #pragma unroll
            for (int mi = 0; mi < 4; ++mi) {
                int r = wm + mi * 16 + (lane & 15);
                af[mi] = *(const short8*)&At[r * 64 + (ko ^ ((r & 7) << 3))];
            }
            #pragma unroll
            for (int ni = 0; ni < 4; ++ni) {
                int r = wn + ni * 16 + (lane & 15);
                bf[ni] = *(const short8*)&Bt[r * 64 + (ko ^ ((r & 7) << 3))];
            }
            #pragma unroll
            for (int mi = 0; mi < 4; ++mi)
                #pragma unroll
                for (int ni = 0; ni < 4; ++ni)
                    acc[mi][ni] = __builtin_amdgcn_mfma_f32_16x16x32_bf16(af[mi], bf[ni], acc[mi][ni], 0, 0, 0);
        }
        __syncthreads();
    }

    float mnv[4];
    #pragma unroll
    for (int ni = 0; ni < 4; ++ni) {
        int col = bcol + wn + ni * 16 + (lane & 15);
        mnv[ni] = (col < 25000) ? mnorm[col] : INF_F;
    }
    #pragma unroll
    for (int mi = 0; mi < 4; ++mi) {
        #pragma unroll
        for (int r = 0; r < 4; ++r) {
            float v = INF_F;
            #pragma unroll
            for (int ni = 0; ni < 4; ++ni) v = fminf(v, mnv[ni] - 2.0f * acc[mi][ni][r]);
            #pragma unroll
            for (int s = 1; s < 16; s <<= 1) v = fminf(v, __shfl_xor(v, s, 64));
            if ((lane & 15) == 0) {
                int row = brow + wm + mi * 16 + (lane >> 4) * 4 + r;
                float sq = v + fnorm[row];
                atomicMin((unsigned*)&ps_sq[row], __float_as_uint(sq));  // sq >= 0
            }
        }
    }
}

// ---------------- output 0: sqrt ----------------
__global__ void k_out0(const float* __restrict__ ps_sq, float* __restrict__ out0) {
    int i = blockIdx.x * 256 + threadIdx.x;
    if (i < 8192) out0[i] = sqrtf(fmaxf(ps_sq[i], 0.0f));
}

// ---------------- per-batch candidate gather (margin-robust argmax) ----------------
// Compact global list (pix, batch); per-batch cap 8 -> ncand <= 64.
__global__ void k_cand(const float* __restrict__ ps_sq, int* ncand, int* cand_pix, int* cand_batch) {
    __shared__ float smax[4];
    __shared__ int scnt;
    int b = blockIdx.x, t = threadIdx.x, wid = t >> 6, lane = t & 63;
    const float* base = ps_sq + b * 1024;
    float v[4]; float m = -INF_F;
    #pragma unroll
    for (int i = 0; i < 4; ++i) { v[i] = base[t + i * 256]; m = fmaxf(m, v[i]); }
    #pragma unroll
    for (int s = 1; s < 64; s <<= 1) m = fmaxf(m, __shfl_xor(m, s, 64));
    if (lane == 0) smax[wid] = m;
    if (t == 0) scnt = 0;
    __syncthreads();
    float bm = fmaxf(fmaxf(smax[0], smax[1]), fmaxf(smax[2], smax[3]));
    #pragma unroll
    for (int i = 0; i < 4; ++i) {
        if (v[i] >= bm - 8.0f) {            // margin >> 2x worst-case bf16 dot error
            int s = atomicAdd(&scnt, 1);
            if (s < 8) {
                int g = atomicAdd(ncand, 1);
                if (g < 64) { cand_pix[g] = b * 1024 + t + i * 256; cand_batch[g] = b; }
            }
        }
    }
}

// ---------------- exact fp32 min-dist for all candidates, one mb pass ----------------
// Candidate vectors hoisted into registers (8 cands x 8 floats/lane): no LDS reads.
__global__ void k_score(const float* __restrict__ fv, const float* __restrict__ mb,
                        const int* __restrict__ ncand, const int* __restrict__ cand_pix,
                        float* __restrict__ cand_val) {
    int nc_tot = ncand[0]; if (nc_tot > 64) nc_tot = 64;
    int c0 = blockIdx.y * 8;
    if (c0 >= nc_tot) return;
    int nc = nc_tot - c0; if (nc > 8) nc = 8;
    int t = threadIdx.x, wid = t >> 6, lane = t & 63;
    float f[8][8];
    #pragma unroll
    for (int c = 0; c < 8; ++c) {
        int pix = cand_pix[c0 + (c < nc ? c : 0)];
        const float4* sp = (const float4*)(fv + (size_t)pix * 512) + lane * 2;
        float4 a0 = sp[0], a1 = sp[1];
        f[c][0]=a0.x; f[c][1]=a0.y; f[c][2]=a0.z; f[c][3]=a0.w;
        f[c][4]=a1.x; f[c][5]=a1.y; f[c][6]=a1.z; f[c][7]=a1.w;
    }
    float cmin[8];
    #pragma unroll
    for (int c = 0; c < 8; ++c) cmin[c] = INF_F;
    int rbase = blockIdx.x * 256 + wid * 64;
    for (int i = 0; i < 64; ++i) {
        int r = rbase + i;
        if (r >= 25000) break;
        const float4* mp = (const float4*)(mb + (size_t)r * 512) + lane * 2;
        float4 m0 = mp[0], m1 = mp[1];
        float mv[8] = {m0.x, m0.y, m0.z, m0.w, m1.x, m1.y, m1.z, m1.w};
        #pragma unroll
        for (int c = 0; c < 8; ++c) {
            float p = 0.f;
            #pragma unroll
            for (int e = 0; e < 8; ++e) { float d = mv[e] - f[c][e]; p += d * d; }
            #pragma unroll
            for (int s = 1; s < 64; s <<= 1) p += __shfl_xor(p, s, 64);
            cmin[c] = fminf(cmin[c], p);
        }
    }
    #pragma unroll
    for (int c = 0; c < 8; ++c) {
        if (c < nc && lane == 0)
            atomicMin((unsigned*)&cand_val[c0 + c], __float_as_uint(cmin[c]));
    }
}

// ---------------- exact argmax (ties -> lower pixel index, matches jnp.argmax) ----------------
__global__ void k_argmax(const int* ncand, const int* cand_pix, const int* cand_batch,
                         const float* cand_val, int* sel_pix) {
    int b = blockIdx.x, lane = threadIdx.x;
    int n = ncand[0]; if (n > 64) n = 64;
    float v = -INF_F; int pix = 0x7fffffff;
    if (lane < n && cand_batch[lane] == b) { v = cand_val[lane]; pix = cand_pix[lane]; }
    #pragma unroll
    for (int s = 1; s < 64; s <<= 1) {
        float ov = __shfl_xor(v, s, 64); int oi = __shfl_xor(pix, s, 64);
        if (ov > v || (ov == v && oi < pix)) { v = ov; pix = oi; }
    }
    if (lane == 0) sel_pix[b] = (pix == 0x7fffffff) ? b * 1024 : pix;
}

// ---------------- exact fp32 distances of the 8 winners to all mb ----------------
// Winner vectors hoisted into registers: no LDS reads.
__global__ void k_dists(const float* __restrict__ fv, const float* __restrict__ mb,
                        const int* __restrict__ sel_pix, float* __restrict__ exact_d) {
    int t = threadIdx.x, wid = t >> 6, lane = t & 63;
    float f[8][8];
    #pragma unroll
    for (int b = 0; b < 8; ++b) {
        const float4* sp = (const float4*)(fv + (size_t)sel_pix[b] * 512) + lane * 2;
        float4 a0 = sp[0], a1 = sp[1];
        f[b][0]=a0.x; f[b][1]=a0.y; f[b][2]=a0.z; f[b][3]=a0.w;
        f[b][4]=a1.x; f[b][5]=a1.y; f[b][6]=a1.z; f[b][7]=a1.w;
    }
    int rbase = blockIdx.x * 256 + wid * 64;
    for (int i = 0; i < 64; ++i) {
        int r = rbase + i;
        if (r >= 25000) break;
        const float4* mp = (const float4*)(mb + (size_t)r * 512) + lane * 2;
        float4 m0 = mp[0], m1 = mp[1];
        float mv[8] = {m0.x, m0.y, m0.z, m0.w, m1.x, m1.y, m1.z, m1.w};
        #pragma unroll
        for (int b = 0; b < 8; ++b) {
            float p = 0.f;
            #pragma unroll
            for (int e = 0; e < 8; ++e) { float d = mv[e] - f[b][e]; p += d * d; }
            #pragma unroll
            for (int s = 1; s < 64; s <<= 1) p += __shfl_xor(p, s, 64);
            if (lane == 0) exact_d[b * 25000 + r] = p;
        }
    }
}

// ---------------- top-b (ascending dist, jax tie order) + softmax -> image_scores ----------------
__global__ void k_final(const float* __restrict__ exact_d, const int* __restrict__ bptr,
                        float* __restrict__ out_img) {
    __shared__ float rv[4]; __shared__ int ri[4];
    __shared__ float seld[128];
    __shared__ float lastV_s; __shared__ int lastI_s;
    int b = blockIdx.x, t = threadIdx.x, wid = t >> 6, lane = t & 63;
    int bval = bptr[0]; if (bval > 128) bval = 128; if (bval < 1) bval = 1;
    const float* dv = exact_d + b * 25000;
    float lastV = -INF_F; int lastI = -1;
    for (int k = 0; k < bval; ++k) {
        float bv = INF_F; int bi = 0x7fffffff;
        for (int r = t; r < 25000; r += 256) {
            float vv = dv[r];
            bool after = (vv > lastV) || (vv == lastV && r > lastI);
            if (after && (vv < bv || (vv == bv && r < bi))) { bv = vv; bi = r; }
        }
        #pragma unroll
        for (int s = 1; s < 64; s <<= 1) {
            float ov = __shfl_xor(bv, s, 64); int oi = __shfl_xor(bi, s, 64);
            if (ov < bv || (ov == bv && oi < bi)) { bv = ov; bi = oi; }
        }
        if (lane == 0) { rv[wid] = bv; ri[wid] = bi; }
        __syncthreads();
        if (t == 0) {
            float fbv = rv[0]; int fbi = ri[0];
            for (int w = 1; w < 4; ++w)
                if (rv[w] < fbv || (rv[w] == fbv && ri[w] < fbi)) { fbv = rv[w]; fbi = ri[w]; }
            seld[k] = sqrtf(fbv);
            lastV_s = fbv; lastI_s = fbi;
        }
        __syncthreads();
        lastV = lastV_s; lastI = lastI_s;
    }
    if (t == 0) {
        float d0 = seld[0];
        float img = d0;
        if (bval > 1) {
            float m = -INF_F;
            for (int k = 0; k < bval; ++k) m = fmaxf(m, seld[k]);
            float s = 0.f;
            for (int k = 0; k < bval; ++k) s += expf(seld[k] - m);
            float p0 = expf(seld[0] - m) / s;
            img = d0 * (1.0f - p0);
        }
        out_img[b] = img;
    }
}

extern "C" void kernel_launch(void* const* d_in, const int* in_sizes, int n_in,
                              void* d_out, int out_size, void* d_ws, size_t ws_size,
                              hipStream_t stream) {
    const float* fv = (const float*)d_in[0];   // 8192 x 512
    const float* mb = (const float*)d_in[1];   // 25000 x 512
    const int*   bp = (const int*)d_in[2];     // scalar b
    float* out = (float*)d_out;                // [0..8191]=pixel_scores, [8192..8199]=image_scores

    char* w = (char*)d_ws;                     // ~36 MB
    unsigned short* fvb = (unsigned short*)w;                       // 8,388,608 B
    unsigned short* mbb = (unsigned short*)(w + 8388608);           // 25,600,000 B
    size_t o = 8388608 + 25600000;
    float* fnorm    = (float*)(w + o); o += 32768;
    float* mnorm    = (float*)(w + o); o += 100352;
    float* ps_sq    = (float*)(w + o); o += 32768;
    int*   ncand    = (int*)(w + o);   o += 256;
    int*   cand_pix = (int*)(w + o);   o += 256;
    int*   cand_bat = (int*)(w + o);   o += 256;
    float* cand_val = (float*)(w + o); o += 256;
    int*   sel_pix  = (int*)(w + o);   o += 256;
    float* exact_d  = (float*)(w + o); o += 800000;

    k_init<<<32, 256, 0, stream>>>(ps_sq, ncand, cand_val);
    k_conv<<<2048, 256, 0, stream>>>(fv, fvb, fnorm, 8192);
    k_conv<<<6250, 256, 0, stream>>>(mb, mbb, mnorm, 25000);
    k_gemm_min<<<12544, 256, 0, stream>>>(fvb, mbb, fnorm, mnorm, ps_sq);
    k_out0<<<32, 256, 0, stream>>>(ps_sq, out);
    k_cand<<<8, 256, 0, stream>>>(ps_sq, ncand, cand_pix, cand_bat);
    k_score<<<dim3(98, 8), 256, 0, stream>>>(fv, mb, ncand, cand_pix, cand_val);
    k_argmax<<<8, 64, 0, stream>>>(ncand, cand_pix, cand_bat, cand_val, sel_pix);
    k_dists<<<98, 256, 0, stream>>>(fv, mb, sel_pix, exact_d);
    k_final<<<8, 256, 0, stream>>>(exact_d, bp, out + 8192);
}

// Round 3
// 671.006 us; speedup vs baseline: 1.7109x; 1.1263x over previous
//
#include <hip/hip_runtime.h>
#include <hip/hip_bf16.h>

typedef __attribute__((ext_vector_type(8))) short short8;
typedef __attribute__((ext_vector_type(4))) float f32x4;

#define INF_F 3.4e38f

__device__ __forceinline__ void gload16(const void* g, void* l) {
    __builtin_amdgcn_global_load_lds((const __attribute__((address_space(1))) unsigned*)g,
                                     (__attribute__((address_space(3))) unsigned*)l, 16, 0, 0);
}

// ---------------- fp32 -> bf16 + row norms (512 cols) for BOTH fv and mb, + init ----------------
__global__ void k_conv(const float* __restrict__ fv, const float* __restrict__ mbp,
                       unsigned short* __restrict__ fvb, unsigned short* __restrict__ mbb,
                       float* __restrict__ fnorm, float* __restrict__ mnorm,
                       float* ps_sq, int* ncand, float* cand_val) {
    int t = threadIdx.x, wid = t >> 6, lane = t & 63;
    if (blockIdx.x == 0) {
        if (t == 0) ncand[0] = 0;
        if (t < 64) ((unsigned*)cand_val)[t] = 0x7f800000u;
    }
    int row = blockIdx.x * 4 + wid;
    const float* in; unsigned short* outb; float* norm; int r;
    if (row < 8192) {
        in = fv; outb = fvb; norm = fnorm; r = row;
        if (lane == 0) ((unsigned*)ps_sq)[row] = 0x7f800000u;   // +inf init
    } else if (row < 33192) {
        in = mbp; outb = mbb; norm = mnorm; r = row - 8192;
    } else return;
    const float4* p = (const float4*)(in + (size_t)r * 512) + lane * 2;
    float4 a = p[0], b = p[1];
    float n = a.x*a.x + a.y*a.y + a.z*a.z + a.w*a.w
            + b.x*b.x + b.y*b.y + b.z*b.z + b.w*b.w;
    float vals[8] = {a.x, a.y, a.z, a.w, b.x, b.y, b.z, b.w};
    unsigned short h[8];
    #pragma unroll
    for (int e = 0; e < 8; ++e) {
        unsigned u = __float_as_uint(vals[e]);
        h[e] = (unsigned short)((u + 0x7fffu + ((u >> 16) & 1u)) >> 16);  // RNE
    }
    *(uint4*)(outb + (size_t)r * 512 + lane * 8) = *(uint4*)h;
    #pragma unroll
    for (int s = 1; s < 64; s <<= 1) n += __shfl_xor(n, s, 64);
    if (lane == 0) norm[r] = n;
}

// ---------------- fused GEMM + per-row min (unchanged: at m97-structure ceiling) ----------------
__global__ __launch_bounds__(256, 2)
void k_gemm_min(const unsigned short* __restrict__ A, const unsigned short* __restrict__ B,
                const float* __restrict__ fnorm, const float* __restrict__ mnorm,
                float* __restrict__ ps_sq) {
    __shared__ unsigned short At[128 * 64];
    __shared__ unsigned short Bt[128 * 64];
    int tid = threadIdx.x, wid = tid >> 6, lane = tid & 63;
    int bid = blockIdx.x;
    int pos = bid >> 3;
    int rb = ((bid & 7) << 3) | (pos & 7);   // 0..63
    int cb = pos >> 3;                        // 0..195
    int brow = rb * 128, bcol = cb * 128;
    int wm = (wid >> 1) * 64, wn = (wid & 1) * 64;

    f32x4 acc[4][4] = {};
    int lr = lane >> 3;
    int lkswz = ((lane & 7) ^ lr) * 8;        // pre-swizzled source column (elems)

    for (int k0 = 0; k0 < 512; k0 += 64) {
        #pragma unroll
        for (int c = 0; c < 4; ++c) {
            int ch = wid + c * 4;
            int row = ch * 8 + lr;
            gload16(A + (size_t)(brow + row) * 512 + k0 + lkswz, &At[ch * 512]);
            int srow = bcol + row; if (srow > 24999) srow = 24999;
            gload16(B + (size_t)srow * 512 + k0 + lkswz, &Bt[ch * 512]);
        }
        __syncthreads();
        #pragma unroll
        for (int kk = 0; kk < 2; ++kk) {
            short8 af[4], bf[4];
            int ko = kk * 32 + (lane >> 4) * 8;
            #pragma unroll
            for (int mi = 0; mi < 4; ++mi) {
                int r = wm + mi * 16 + (lane & 15);
                af[mi] = *(const short8*)&At[r * 64 + (ko ^ ((r & 7) << 3))];
            }
            #pragma unroll
            for (int ni = 0; ni < 4; ++ni) {
                int r = wn + ni * 16 + (lane & 15);
                bf[ni] = *(const short8*)&Bt[r * 64 + (ko ^ ((r & 7) << 3))];
            }
            #pragma unroll
            for (int mi = 0; mi < 4; ++mi)
                #pragma unroll
                for (int ni = 0; ni < 4; ++ni)
                    acc[mi][ni] = __builtin_amdgcn_mfma_f32_16x16x32_bf16(af[mi], bf[ni], acc[mi][ni], 0, 0, 0);
        }
        __syncthreads();
    }

    float mnv[4];
    #pragma unroll
    for (int ni = 0; ni < 4; ++ni) {
        int col = bcol + wn + ni * 16 + (lane & 15);
        mnv[ni] = (col < 25000) ? mnorm[col] : INF_F;
    }
    #pragma unroll
    for (int mi = 0; mi < 4; ++mi) {
        #pragma unroll
        for (int r = 0; r < 4; ++r) {
            float v = INF_F;
            #pragma unroll
            for (int ni = 0; ni < 4; ++ni) v = fminf(v, mnv[ni] - 2.0f * acc[mi][ni][r]);
            #pragma unroll
            for (int s = 1; s < 16; s <<= 1) v = fminf(v, __shfl_xor(v, s, 64));
            if ((lane & 15) == 0) {
                int row = brow + wm + mi * 16 + (lane >> 4) * 4 + r;
                float sq = v + fnorm[row];
                atomicMin((unsigned*)&ps_sq[row], __float_as_uint(sq));
            }
        }
    }
}

// ---------------- out0 + per-batch candidate gather ----------------
__global__ void k_cand(const float* __restrict__ ps_sq, float* __restrict__ out0,
                       int* ncand, int* cand_pix, int* cand_batch) {
    __shared__ float smax[4];
    __shared__ int scnt;
    int b = blockIdx.x, t = threadIdx.x, wid = t >> 6, lane = t & 63;
    const float* base = ps_sq + b * 1024;
    float v[4]; float m = -INF_F;
    #pragma unroll
    for (int i = 0; i < 4; ++i) {
        v[i] = base[t + i * 256];
        out0[b * 1024 + t + i * 256] = sqrtf(fmaxf(v[i], 0.0f));
        m = fmaxf(m, v[i]);
    }
    #pragma unroll
    for (int s = 1; s < 64; s <<= 1) m = fmaxf(m, __shfl_xor(m, s, 64));
    if (lane == 0) smax[wid] = m;
    if (t == 0) scnt = 0;
    __syncthreads();
    float bm = fmaxf(fmaxf(smax[0], smax[1]), fmaxf(smax[2], smax[3]));
    #pragma unroll
    for (int i = 0; i < 4; ++i) {
        if (v[i] >= bm - 8.0f) {            // margin >> 2x worst-case bf16 dot error
            int s = atomicAdd(&scnt, 1);
            if (s < 8) {
                int g = atomicAdd(ncand, 1);
                if (g < 64) { cand_pix[g] = b * 1024 + t + i * 256; cand_batch[g] = b; }
            }
        }
    }
}

// ---------------- exact fp32 min-dist for all candidates (64 rows/block, 391 blocks) ----------------
__global__ void k_score(const float* __restrict__ fv, const float* __restrict__ mb,
                        const int* __restrict__ ncand, const int* __restrict__ cand_pix,
                        float* __restrict__ cand_val) {
    int nc_tot = ncand[0]; if (nc_tot > 64) nc_tot = 64;
    int c0 = blockIdx.y * 8;
    if (c0 >= nc_tot) return;
    int nc = nc_tot - c0; if (nc > 8) nc = 8;
    int t = threadIdx.x, wid = t >> 6, lane = t & 63;
    float f[8][8];
    #pragma unroll
    for (int c = 0; c < 8; ++c) {
        int pix = cand_pix[c0 + (c < nc ? c : 0)];
        const float4* sp = (const float4*)(fv + (size_t)pix * 512) + lane * 2;
        float4 a0 = sp[0], a1 = sp[1];
        f[c][0]=a0.x; f[c][1]=a0.y; f[c][2]=a0.z; f[c][3]=a0.w;
        f[c][4]=a1.x; f[c][5]=a1.y; f[c][6]=a1.z; f[c][7]=a1.w;
    }
    float cmin[8];
    #pragma unroll
    for (int c = 0; c < 8; ++c) cmin[c] = INF_F;
    int rbase = blockIdx.x * 64 + wid * 16;
    for (int i = 0; i < 16; ++i) {
        int r = rbase + i;
        if (r >= 25000) break;
        const float4* mp = (const float4*)(mb + (size_t)r * 512) + lane * 2;
        float4 m0 = mp[0], m1 = mp[1];
        float mv[8] = {m0.x, m0.y, m0.z, m0.w, m1.x, m1.y, m1.z, m1.w};
        #pragma unroll
        for (int c = 0; c < 8; ++c) {
            float p = 0.f;
            #pragma unroll
            for (int e = 0; e < 8; ++e) { float d = mv[e] - f[c][e]; p += d * d; }
            #pragma unroll
            for (int s = 1; s < 64; s <<= 1) p += __shfl_xor(p, s, 64);
            cmin[c] = fminf(cmin[c], p);
        }
    }
    #pragma unroll
    for (int c = 0; c < 8; ++c) {
        if (c < nc && lane == 0)
            atomicMin((unsigned*)&cand_val[c0 + c], __float_as_uint(cmin[c]));
    }
}

// ---------------- exact argmax (ties -> lower pixel index) ----------------
__global__ void k_argmax(const int* ncand, const int* cand_pix, const int* cand_batch,
                         const float* cand_val, int* sel_pix) {
    int b = blockIdx.x, lane = threadIdx.x;
    int n = ncand[0]; if (n > 64) n = 64;
    float v = -INF_F; int pix = 0x7fffffff;
    if (lane < n && cand_batch[lane] == b) { v = cand_val[lane]; pix = cand_pix[lane]; }
    #pragma unroll
    for (int s = 1; s < 64; s <<= 1) {
        float ov = __shfl_xor(v, s, 64); int oi = __shfl_xor(pix, s, 64);
        if (ov > v || (ov == v && oi < pix)) { v = ov; pix = oi; }
    }
    if (lane == 0) sel_pix[b] = (pix == 0x7fffffff) ? b * 1024 : pix;
}

// ---------------- exact fp32 distances of the 8 winners (64 rows/block, 391 blocks) ----------------
__global__ void k_dists(const float* __restrict__ fv, const float* __restrict__ mb,
                        const int* __restrict__ sel_pix, float* __restrict__ exact_d) {
    int t = threadIdx.x, wid = t >> 6, lane = t & 63;
    float f[8][8];
    #pragma unroll
    for (int b = 0; b < 8; ++b) {
        const float4* sp = (const float4*)(fv + (size_t)sel_pix[b] * 512) + lane * 2;
        float4 a0 = sp[0], a1 = sp[1];
        f[b][0]=a0.x; f[b][1]=a0.y; f[b][2]=a0.z; f[b][3]=a0.w;
        f[b][4]=a1.x; f[b][5]=a1.y; f[b][6]=a1.z; f[b][7]=a1.w;
    }
    int rbase = blockIdx.x * 64 + wid * 16;
    for (int i = 0; i < 16; ++i) {
        int r = rbase + i;
        if (r >= 25000) break;
        const float4* mp = (const float4*)(mb + (size_t)r * 512) + lane * 2;
        float4 m0 = mp[0], m1 = mp[1];
        float mv[8] = {m0.x, m0.y, m0.z, m0.w, m1.x, m1.y, m1.z, m1.w};
        #pragma unroll
        for (int b = 0; b < 8; ++b) {
            float p = 0.f;
            #pragma unroll
            for (int e = 0; e < 8; ++e) { float d = mv[e] - f[b][e]; p += d * d; }
            #pragma unroll
            for (int s = 1; s < 64; s <<= 1) p += __shfl_xor(p, s, 64);
            if (lane == 0) exact_d[b * 25000 + r] = p;
        }
    }
}

// ---------------- top-b (ascending dist, jax tie order) + softmax, 1024 threads ----------------
__global__ __launch_bounds__(1024)
void k_final(const float* __restrict__ exact_d, const int* __restrict__ bptr,
             float* __restrict__ out_img) {
    __shared__ float rv[16]; __shared__ int ri[16];
    __shared__ float seld[128];
    __shared__ float lastV_s; __shared__ int lastI_s;
    int b = blockIdx.x, t = threadIdx.x, wid = t >> 6, lane = t & 63;
    int bval = bptr[0]; if (bval > 128) bval = 128; if (bval < 1) bval = 1;
    const float* dv = exact_d + b * 25000;
    float lastV = -INF_F; int lastI = -1;
    for (int k = 0; k < bval; ++k) {
        float bv = INF_F; int bi = 0x7fffffff;
        for (int r = t; r < 25000; r += 1024) {
            float vv = dv[r];
            bool after = (vv > lastV) || (vv == lastV && r > lastI);
            if (after && (vv < bv || (vv == bv && r < bi))) { bv = vv; bi = r; }
        }
        #pragma unroll
        for (int s = 1; s < 64; s <<= 1) {
            float ov = __shfl_xor(bv, s, 64); int oi = __shfl_xor(bi, s, 64);
            if (ov < bv || (ov == bv && oi < bi)) { bv = ov; bi = oi; }
        }
        if (lane == 0) { rv[wid] = bv; ri[wid] = bi; }
        __syncthreads();
        if (t == 0) {
            float fbv = rv[0]; int fbi = ri[0];
            for (int w = 1; w < 16; ++w)
                if (rv[w] < fbv || (rv[w] == fbv && ri[w] < fbi)) { fbv = rv[w]; fbi = ri[w]; }
            seld[k] = sqrtf(fbv);
            lastV_s = fbv; lastI_s = fbi;
        }
        __syncthreads();
        lastV = lastV_s; lastI = lastI_s;
    }
    if (t == 0) {
        float d0 = seld[0];
        float img = d0;
        if (bval > 1) {
            float m = -INF_F;
            for (int k = 0; k < bval; ++k) m = fmaxf(m, seld[k]);
            float s = 0.f;
            for (int k = 0; k < bval; ++k) s += expf(seld[k] - m);
            float p0 = expf(seld[0] - m) / s;
            img = d0 * (1.0f - p0);
        }
        out_img[b] = img;
    }
}

extern "C" void kernel_launch(void* const* d_in, const int* in_sizes, int n_in,
                              void* d_out, int out_size, void* d_ws, size_t ws_size,
                              hipStream_t stream) {
    const float* fv = (const float*)d_in[0];   // 8192 x 512
    const float* mb = (const float*)d_in[1];   // 25000 x 512
    const int*   bp = (const int*)d_in[2];     // scalar b
    float* out = (float*)d_out;                // [0..8191]=pixel_scores, [8192..8199]=image_scores

    char* w = (char*)d_ws;                     // ~35 MB
    unsigned short* fvb = (unsigned short*)w;                       // 8,388,608 B
    unsigned short* mbb = (unsigned short*)(w + 8388608);           // 25,600,000 B
    size_t o = 8388608 + 25600000;
    float* fnorm    = (float*)(w + o); o += 32768;
    float* mnorm    = (float*)(w + o); o += 100352;
    float* ps_sq    = (float*)(w + o); o += 32768;
    int*   ncand    = (int*)(w + o);   o += 256;
    int*   cand_pix = (int*)(w + o);   o += 256;
    int*   cand_bat = (int*)(w + o);   o += 256;
    float* cand_val = (float*)(w + o); o += 256;
    int*   sel_pix  = (int*)(w + o);   o += 256;
    float* exact_d  = (float*)(w + o); o += 800000;

    k_conv<<<8298, 256, 0, stream>>>(fv, mb, fvb, mbb, fnorm, mnorm, ps_sq, ncand, cand_val);
    k_gemm_min<<<12544, 256, 0, stream>>>(fvb, mbb, fnorm, mnorm, ps_sq);
    k_cand<<<8, 256, 0, stream>>>(ps_sq, out, ncand, cand_pix, cand_bat);
    k_score<<<dim3(391, 8), 256, 0, stream>>>(fv, mb, ncand, cand_pix, cand_val);
    k_argmax<<<8, 64, 0, stream>>>(ncand, cand_pix, cand_bat, cand_val, sel_pix);
    k_dists<<<391, 256, 0, stream>>>(fv, mb, sel_pix, exact_d);
    k_final<<<8, 1024, 0, stream>>>(exact_d, bp, out + 8192);
}

// Round 5
// 472.634 us; speedup vs baseline: 2.4290x; 1.4197x over previous
//
#include <hip/hip_runtime.h>
#include <hip/hip_bf16.h>

typedef __attribute__((ext_vector_type(8))) short short8;
typedef __attribute__((ext_vector_type(4))) float f32x4;

#define INF_F 3.4e38f

__device__ __forceinline__ void gload16(const void* g, void* l) {
    __builtin_amdgcn_global_load_lds((const __attribute__((address_space(1))) unsigned*)g,
                                     (__attribute__((address_space(3))) unsigned*)l, 16, 0, 0);
}

// ---------------- fp32 -> bf16 + row norms (512 cols) for BOTH fv and mb, + init ----------------
__global__ void k_conv(const float* __restrict__ fv, const float* __restrict__ mbp,
                       unsigned short* __restrict__ fvb, unsigned short* __restrict__ mbb,
                       float* __restrict__ fnorm, float* __restrict__ mnorm,
                       float* ps_sq, int* ncand, float* cand_val) {
    int t = threadIdx.x, wid = t >> 6, lane = t & 63;
    if (blockIdx.x == 0) {
        if (t == 0) ncand[0] = 0;
        if (t < 64) ((unsigned*)cand_val)[t] = 0x7f800000u;
    }
    int row = blockIdx.x * 4 + wid;
    const float* in; unsigned short* outb; float* norm; int r;
    if (row < 8192) {
        in = fv; outb = fvb; norm = fnorm; r = row;
        if (lane == 0) ((unsigned*)ps_sq)[row] = 0x7f800000u;   // +inf init
    } else if (row < 33192) {
        in = mbp; outb = mbb; norm = mnorm; r = row - 8192;
    } else return;
    const float4* p = (const float4*)(in + (size_t)r * 512) + lane * 2;
    float4 a = p[0], b = p[1];
    float n = a.x*a.x + a.y*a.y + a.z*a.z + a.w*a.w
            + b.x*b.x + b.y*b.y + b.z*b.z + b.w*b.w;
    float vals[8] = {a.x, a.y, a.z, a.w, b.x, b.y, b.z, b.w};
    unsigned short h[8];
    #pragma unroll
    for (int e = 0; e < 8; ++e) {
        unsigned u = __float_as_uint(vals[e]);
        h[e] = (unsigned short)((u + 0x7fffu + ((u >> 16) & 1u)) >> 16);  // RNE
    }
    *(uint4*)(outb + (size_t)r * 512 + lane * 8) = *(uint4*)h;
    #pragma unroll
    for (int s = 1; s < 64; s <<= 1) n += __shfl_xor(n, s, 64);
    if (lane == 0) norm[r] = n;
}

// ---------------- fused GEMM + per-row min (unchanged: at m97-structure ceiling) ----------------
__global__ __launch_bounds__(256, 2)
void k_gemm_min(const unsigned short* __restrict__ A, const unsigned short* __restrict__ B,
                const float* __restrict__ fnorm, const float* __restrict__ mnorm,
                float* __restrict__ ps_sq) {
    __shared__ unsigned short At[128 * 64];
    __shared__ unsigned short Bt[128 * 64];
    int tid = threadIdx.x, wid = tid >> 6, lane = tid & 63;
    int bid = blockIdx.x;
    int pos = bid >> 3;
    int rb = ((bid & 7) << 3) | (pos & 7);   // 0..63
    int cb = pos >> 3;                        // 0..195
    int brow = rb * 128, bcol = cb * 128;
    int wm = (wid >> 1) * 64, wn = (wid & 1) * 64;

    f32x4 acc[4][4] = {};
    int lr = lane >> 3;
    int lkswz = ((lane & 7) ^ lr) * 8;        // pre-swizzled source column (elems)

    for (int k0 = 0; k0 < 512; k0 += 64) {
        #pragma unroll
        for (int c = 0; c < 4; ++c) {
            int ch = wid + c * 4;
            int row = ch * 8 + lr;
            gload16(A + (size_t)(brow + row) * 512 + k0 + lkswz, &At[ch * 512]);
            int srow = bcol + row; if (srow > 24999) srow = 24999;
            gload16(B + (size_t)srow * 512 + k0 + lkswz, &Bt[ch * 512]);
        }
        __syncthreads();
        #pragma unroll
        for (int kk = 0; kk < 2; ++kk) {
            short8 af[4], bf[4];
            int ko = kk * 32 + (lane >> 4) * 8;
            #pragma unroll
            for (int mi = 0; mi < 4; ++mi) {
                int r = wm + mi * 16 + (lane & 15);
                af[mi] = *(const short8*)&At[r * 64 + (ko ^ ((r & 7) << 3))];
            }
            #pragma unroll
            for (int ni = 0; ni < 4; ++ni) {
                int r = wn + ni * 16 + (lane & 15);
                bf[ni] = *(const short8*)&Bt[r * 64 + (ko ^ ((r & 7) << 3))];
            }
            #pragma unroll
            for (int mi = 0; mi < 4; ++mi)
                #pragma unroll
                for (int ni = 0; ni < 4; ++ni)
                    acc[mi][ni] = __builtin_amdgcn_mfma_f32_16x16x32_bf16(af[mi], bf[ni], acc[mi][ni], 0, 0, 0);
        }
        __syncthreads();
    }

    float mnv[4];
    #pragma unroll
    for (int ni = 0; ni < 4; ++ni) {
        int col = bcol + wn + ni * 16 + (lane & 15);
        mnv[ni] = (col < 25000) ? mnorm[col] : INF_F;
    }
    #pragma unroll
    for (int mi = 0; mi < 4; ++mi) {
        #pragma unroll
        for (int r = 0; r < 4; ++r) {
            float v = INF_F;
            #pragma unroll
            for (int ni = 0; ni < 4; ++ni) v = fminf(v, mnv[ni] - 2.0f * acc[mi][ni][r]);
            #pragma unroll
            for (int s = 1; s < 16; s <<= 1) v = fminf(v, __shfl_xor(v, s, 64));
            if ((lane & 15) == 0) {
                int row = brow + wm + mi * 16 + (lane >> 4) * 4 + r;
                float sq = v + fnorm[row];
                atomicMin((unsigned*)&ps_sq[row], __float_as_uint(sq));
            }
        }
    }
}

// ---------------- out0 + per-batch candidate gather ----------------
__global__ void k_cand(const float* __restrict__ ps_sq, float* __restrict__ out0,
                       int* ncand, int* cand_pix, int* cand_batch) {
    __shared__ float smax[4];
    __shared__ int scnt;
    int b = blockIdx.x, t = threadIdx.x, wid = t >> 6, lane = t & 63;
    const float* base = ps_sq + b * 1024;
    float v[4]; float m = -INF_F;
    #pragma unroll
    for (int i = 0; i < 4; ++i) {
        v[i] = base[t + i * 256];
        out0[b * 1024 + t + i * 256] = sqrtf(fmaxf(v[i], 0.0f));
        m = fmaxf(m, v[i]);
    }
    #pragma unroll
    for (int s = 1; s < 64; s <<= 1) m = fmaxf(m, __shfl_xor(m, s, 64));
    if (lane == 0) smax[wid] = m;
    if (t == 0) scnt = 0;
    __syncthreads();
    float bm = fmaxf(fmaxf(smax[0], smax[1]), fmaxf(smax[2], smax[3]));
    #pragma unroll
    for (int i = 0; i < 4; ++i) {
        if (v[i] >= bm - 8.0f) {            // margin >> 2x worst-case bf16 dot error
            int s = atomicAdd(&scnt, 1);
            if (s < 8) {
                int g = atomicAdd(ncand, 1);
                if (g < 64) { cand_pix[g] = b * 1024 + t + i * 256; cand_batch[g] = b; }
            }
        }
    }
}

// ---------------- exact fp32 min-dist, 4 candidates/block in NAMED registers ----------------
__global__ __launch_bounds__(256, 4)
void k_score(const float* __restrict__ fv, const float* __restrict__ mb,
             const int* __restrict__ ncand, const int* __restrict__ cand_pix,
             float* __restrict__ cand_val) {
    int nct = ncand[0]; if (nct > 64) nct = 64;
    int c0 = blockIdx.y * 4;
    if (c0 >= nct) return;
    int t = threadIdx.x, wid = t >> 6, lane = t & 63;

    int p0i = cand_pix[c0];
    int p1i = cand_pix[c0 + 1 < nct ? c0 + 1 : c0];
    int p2i = cand_pix[c0 + 2 < nct ? c0 + 2 : c0];
    int p3i = cand_pix[c0 + 3 < nct ? c0 + 3 : c0];
    const float4* s0 = (const float4*)(fv + (size_t)p0i * 512) + lane * 2;
    const float4* s1 = (const float4*)(fv + (size_t)p1i * 512) + lane * 2;
    const float4* s2 = (const float4*)(fv + (size_t)p2i * 512) + lane * 2;
    const float4* s3 = (const float4*)(fv + (size_t)p3i * 512) + lane * 2;
    float4 ca0 = s0[0], ca1 = s0[1];
    float4 cb0 = s1[0], cb1 = s1[1];
    float4 cc0 = s2[0], cc1 = s2[1];
    float4 cd0 = s3[0], cd1 = s3[1];

    float m0v = INF_F, m1v = INF_F, m2v = INF_F, m3v = INF_F;
    int rbase = blockIdx.x * 64 + wid * 16;
    for (int i = 0; i < 16; ++i) {
        int r = rbase + i;
        if (r >= 25000) break;
        const float4* mp = (const float4*)(mb + (size_t)r * 512) + lane * 2;
        float4 x0 = mp[0], x1 = mp[1];
        float d, p0 = 0.f, p1 = 0.f, p2 = 0.f, p3 = 0.f;
        d = x0.x-ca0.x; p0 += d*d;  d = x0.y-ca0.y; p0 += d*d;  d = x0.z-ca0.z; p0 += d*d;  d = x0.w-ca0.w; p0 += d*d;
        d = x1.x-ca1.x; p0 += d*d;  d = x1.y-ca1.y; p0 += d*d;  d = x1.z-ca1.z; p0 += d*d;  d = x1.w-ca1.w; p0 += d*d;
        d = x0.x-cb0.x; p1 += d*d;  d = x0.y-cb0.y; p1 += d*d;  d = x0.z-cb0.z; p1 += d*d;  d = x0.w-cb0.w; p1 += d*d;
        d = x1.x-cb1.x; p1 += d*d;  d = x1.y-cb1.y; p1 += d*d;  d = x1.z-cb1.z; p1 += d*d;  d = x1.w-cb1.w; p1 += d*d;
        d = x0.x-cc0.x; p2 += d*d;  d = x0.y-cc0.y; p2 += d*d;  d = x0.z-cc0.z; p2 += d*d;  d = x0.w-cc0.w; p2 += d*d;
        d = x1.x-cc1.x; p2 += d*d;  d = x1.y-cc1.y; p2 += d*d;  d = x1.z-cc1.z; p2 += d*d;  d = x1.w-cc1.w; p2 += d*d;
        d = x0.x-cd0.x; p3 += d*d;  d = x0.y-cd0.y; p3 += d*d;  d = x0.z-cd0.z; p3 += d*d;  d = x0.w-cd0.w; p3 += d*d;
        d = x1.x-cd1.x; p3 += d*d;  d = x1.y-cd1.y; p3 += d*d;  d = x1.z-cd1.z; p3 += d*d;  d = x1.w-cd1.w; p3 += d*d;
        #pragma unroll
        for (int s = 1; s < 64; s <<= 1) {
            p0 += __shfl_xor(p0, s, 64);
            p1 += __shfl_xor(p1, s, 64);
            p2 += __shfl_xor(p2, s, 64);
            p3 += __shfl_xor(p3, s, 64);
        }
        m0v = fminf(m0v, p0); m1v = fminf(m1v, p1);
        m2v = fminf(m2v, p2); m3v = fminf(m3v, p3);
    }
    if (lane < 4 && c0 + lane < nct) {
        float mv = (lane == 0) ? m0v : (lane == 1) ? m1v : (lane == 2) ? m2v : m3v;
        atomicMin((unsigned*)&cand_val[c0 + lane], __float_as_uint(mv));
    }
}

// ---------------- exact argmax -> winning pixel (ties -> lower pixel index) ----------------
__global__ void k_argmax(const int* ncand, const int* cand_pix, const int* cand_batch,
                         const float* cand_val, int* sel_pix) {
    int b = blockIdx.x, lane = threadIdx.x;
    int n = ncand[0]; if (n > 64) n = 64;
    float v = -INF_F; int pix = 0x7fffffff;
    if (lane < n && cand_batch[lane] == b) { v = cand_val[lane]; pix = cand_pix[lane]; }
    #pragma unroll
    for (int s = 1; s < 64; s <<= 1) {
        float ov = __shfl_xor(v, s, 64); int oi = __shfl_xor(pix, s, 64);
        if (ov > v || (ov == v && oi < pix)) { v = ov; pix = oi; }
    }
    if (lane == 0) sel_pix[b] = (pix == 0x7fffffff) ? b * 1024 : pix;
}

// ---------------- exact fp32 distances of winners, 4/block in NAMED registers ----------------
__global__ __launch_bounds__(256, 4)
void k_dists4(const float* __restrict__ fv, const float* __restrict__ mb,
              const int* __restrict__ sel_pix, float* __restrict__ exact_d) {
    int bg = blockIdx.y * 4;                 // batch group: 0..3 or 4..7
    int t = threadIdx.x, wid = t >> 6, lane = t & 63;

    const float4* s0 = (const float4*)(fv + (size_t)sel_pix[bg + 0] * 512) + lane * 2;
    const float4* s1 = (const float4*)(fv + (size_t)sel_pix[bg + 1] * 512) + lane * 2;
    const float4* s2 = (const float4*)(fv + (size_t)sel_pix[bg + 2] * 512) + lane * 2;
    const float4* s3 = (const float4*)(fv + (size_t)sel_pix[bg + 3] * 512) + lane * 2;
    float4 ca0 = s0[0], ca1 = s0[1];
    float4 cb0 = s1[0], cb1 = s1[1];
    float4 cc0 = s2[0], cc1 = s2[1];
    float4 cd0 = s3[0], cd1 = s3[1];

    int rbase = blockIdx.x * 64 + wid * 16;
    for (int i = 0; i < 16; ++i) {
        int r = rbase + i;
        if (r >= 25000) break;
        const float4* mp = (const float4*)(mb + (size_t)r * 512) + lane * 2;
        float4 x0 = mp[0], x1 = mp[1];
        float d, p0 = 0.f, p1 = 0.f, p2 = 0.f, p3 = 0.f;
        d = x0.x-ca0.x; p0 += d*d;  d = x0.y-ca0.y; p0 += d*d;  d = x0.z-ca0.z; p0 += d*d;  d = x0.w-ca0.w; p0 += d*d;
        d = x1.x-ca1.x; p0 += d*d;  d = x1.y-ca1.y; p0 += d*d;  d = x1.z-ca1.z; p0 += d*d;  d = x1.w-ca1.w; p0 += d*d;
        d = x0.x-cb0.x; p1 += d*d;  d = x0.y-cb0.y; p1 += d*d;  d = x0.z-cb0.z; p1 += d*d;  d = x0.w-cb0.w; p1 += d*d;
        d = x1.x-cb1.x; p1 += d*d;  d = x1.y-cb1.y; p1 += d*d;  d = x1.z-cb1.z; p1 += d*d;  d = x1.w-cb1.w; p1 += d*d;
        d = x0.x-cc0.x; p2 += d*d;  d = x0.y-cc0.y; p2 += d*d;  d = x0.z-cc0.z; p2 += d*d;  d = x0.w-cc0.w; p2 += d*d;
        d = x1.x-cc1.x; p2 += d*d;  d = x1.y-cc1.y; p2 += d*d;  d = x1.z-cc1.z; p2 += d*d;  d = x1.w-cc1.w; p2 += d*d;
        d = x0.x-cd0.x; p3 += d*d;  d = x0.y-cd0.y; p3 += d*d;  d = x0.z-cd0.z; p3 += d*d;  d = x0.w-cd0.w; p3 += d*d;
        d = x1.x-cd1.x; p3 += d*d;  d = x1.y-cd1.y; p3 += d*d;  d = x1.z-cd1.z; p3 += d*d;  d = x1.w-cd1.w; p3 += d*d;
        #pragma unroll
        for (int s = 1; s < 64; s <<= 1) {
            p0 += __shfl_xor(p0, s, 64);
            p1 += __shfl_xor(p1, s, 64);
            p2 += __shfl_xor(p2, s, 64);
            p3 += __shfl_xor(p3, s, 64);
        }
        if (lane < 4) {
            float pv = (lane == 0) ? p0 : (lane == 1) ? p1 : (lane == 2) ? p2 : p3;
            exact_d[(size_t)(bg + lane) * 25000 + r] = pv;
        }
    }
}

// ---------------- top-b (ascending dist, jax tie order) + softmax, 1024 threads ----------------
__global__ __launch_bounds__(1024)
void k_final(const float* __restrict__ exact_d, const int* __restrict__ bptr,
             float* __restrict__ out_img) {
    __shared__ float rv[16]; __shared__ int ri[16];
    __shared__ float seld[128];
    __shared__ float lastV_s; __shared__ int lastI_s;
    int b = blockIdx.x, t = threadIdx.x, wid = t >> 6, lane = t & 63;
    int bval = bptr[0]; if (bval > 128) bval = 128; if (bval < 1) bval = 1;
    const float* dv = exact_d + (size_t)b * 25000;
    float lastV = -INF_F; int lastI = -1;
    for (int k = 0; k < bval; ++k) {
        float bv = INF_F; int bi = 0x7fffffff;
        for (int r = t; r < 25000; r += 1024) {
            float vv = dv[r];
            bool after = (vv > lastV) || (vv == lastV && r > lastI);
            if (after && (vv < bv || (vv == bv && r < bi))) { bv = vv; bi = r; }
        }
        #pragma unroll
        for (int s = 1; s < 64; s <<= 1) {
            float ov = __shfl_xor(bv, s, 64); int oi = __shfl_xor(bi, s, 64);
            if (ov < bv || (ov == bv && oi < bi)) { bv = ov; bi = oi; }
        }
        if (lane == 0) { rv[wid] = bv; ri[wid] = bi; }
        __syncthreads();
        if (t == 0) {
            float fbv = rv[0]; int fbi = ri[0];
            for (int w = 1; w < 16; ++w)
                if (rv[w] < fbv || (rv[w] == fbv && ri[w] < fbi)) { fbv = rv[w]; fbi = ri[w]; }
            seld[k] = sqrtf(fbv);
            lastV_s = fbv; lastI_s = fbi;
        }
        __syncthreads();
        lastV = lastV_s; lastI = lastI_s;
    }
    if (t == 0) {
        float d0 = seld[0];
        float img = d0;
        if (bval > 1) {
            float m = -INF_F;
            for (int k = 0; k < bval; ++k) m = fmaxf(m, seld[k]);
            float s = 0.f;
            for (int k = 0; k < bval; ++k) s += expf(seld[k] - m);
            float p0 = expf(seld[0] - m) / s;
            img = d0 * (1.0f - p0);
        }
        out_img[b] = img;
    }
}

extern "C" void kernel_launch(void* const* d_in, const int* in_sizes, int n_in,
                              void* d_out, int out_size, void* d_ws, size_t ws_size,
                              hipStream_t stream) {
    const float* fv = (const float*)d_in[0];   // 8192 x 512
    const float* mb = (const float*)d_in[1];   // 25000 x 512
    const int*   bp = (const int*)d_in[2];     // scalar b
    float* out = (float*)d_out;                // [0..8191]=pixel_scores, [8192..8199]=image_scores

    char* w = (char*)d_ws;                     // ~35 MB total (same footprint as R3, which passed)
    unsigned short* fvb = (unsigned short*)w;                       // 8,388,608 B
    unsigned short* mbb = (unsigned short*)(w + 8388608);           // 25,600,000 B
    size_t o = 8388608 + 25600000;
    float* fnorm    = (float*)(w + o); o += 32768;
    float* mnorm    = (float*)(w + o); o += 100352;
    float* ps_sq    = (float*)(w + o); o += 32768;
    int*   ncand    = (int*)(w + o);   o += 256;
    int*   cand_pix = (int*)(w + o);   o += 256;
    int*   cand_bat = (int*)(w + o);   o += 256;
    float* cand_val = (float*)(w + o); o += 256;
    int*   sel_pix  = (int*)(w + o);   o += 256;
    float* exact_d  = (float*)(w + o); o += 800000;    // 8 x 25000 fp32

    k_conv<<<8298, 256, 0, stream>>>(fv, mb, fvb, mbb, fnorm, mnorm, ps_sq, ncand, cand_val);
    k_gemm_min<<<12544, 256, 0, stream>>>(fvb, mbb, fnorm, mnorm, ps_sq);
    k_cand<<<8, 256, 0, stream>>>(ps_sq, out, ncand, cand_pix, cand_bat);
    k_score<<<dim3(391, 16), 256, 0, stream>>>(fv, mb, ncand, cand_pix, cand_val);
    k_argmax<<<8, 64, 0, stream>>>(ncand, cand_pix, cand_bat, cand_val, sel_pix);
    k_dists4<<<dim3(391, 2), 256, 0, stream>>>(fv, mb, sel_pix, exact_d);
    k_final<<<8, 1024, 0, stream>>>(exact_d, bp, out + 8192);
}